// Round 5
// baseline (258.882 us; speedup 1.0000x reference)
//
#include <hip/hip_runtime.h>
#include <hip/hip_bf16.h>

constexpr int NN  = 50000;
constexpr int NN2 = 50048;
constexpr int NE  = 800000;
constexpr int SCAN_B = 1024;
constexpr int NB = (NN + SCAN_B - 1) / SCAN_B;    // 49 scan blocks
constexpr int GB = (NN + 63) / 64;                // 782 gemm blocks (64 rows each)
constexpr int E4_BLOCKS = (NE / 4 + 255) / 256;   // 782 (edge kernels, 4 edges/thread)

typedef short bf16x8 __attribute__((ext_vector_type(8)));
typedef float f32x4  __attribute__((ext_vector_type(4)));

__device__ __forceinline__ float bfu_to_f(unsigned int u16) {
    return __uint_as_float(u16 << 16);
}
__device__ __forceinline__ unsigned short f_to_bfu(float f) {
    unsigned int u = __float_as_uint(f);
    return (unsigned short)((u + 0x7fffu + ((u >> 16) & 1u)) >> 16);
}
__device__ __forceinline__ void split_bf16(float v, unsigned short& h, unsigned short& l) {
    h = f_to_bfu(v);
    l = f_to_bfu(v - bfu_to_f(h));
}

// ---------- W prep (transposed bf16 hi/lo tables Wt[n][k]) + deg zeroing ----------
// blocks [0,96): W split/transpose; blocks [96,145): zero deg[NN2]
__global__ __launch_bounds__(256) void wprep_kernel(
        const float* __restrict__ W1, const float* __restrict__ W2,
        unsigned short* __restrict__ wt1h, unsigned short* __restrict__ wt1l,
        unsigned short* __restrict__ wt2h, unsigned short* __restrict__ wt2l,
        int* __restrict__ deg) {
    const int bid = blockIdx.x;
    if (bid >= 96) {
        int i = ((bid - 96) * 256 + threadIdx.x) * 4;
        if (i < NN2) *reinterpret_cast<int4*>(deg + i) = make_int4(0, 0, 0, 0);
        return;
    }
    int i = bid * 256 + threadIdx.x;
    if (i < 128 * 128) {
        int n = i >> 7, k = i & 127;
        unsigned short h, l;
        split_bf16(W1[k * 128 + n], h, l);
        wt1h[i] = h; wt1l[i] = l;
    }
    i -= 128 * 128;
    if (i >= 0 && i < 64 * 128) {
        int n = i >> 7, k = i & 127;
        unsigned short h, l;
        split_bf16(W2[k * 64 + n], h, l);
        wt2h[i] = h; wt2l[i] = l;
    }
}

// ---------- MFMA GEMM (bf16 split, fp32-accurate) + optional fused degree histogram ----------
// C[M x BN] = X[M x 128] @ W[128 x BN], H stored bf16 row-major stride BN.
// A-tile (64 x 128) staged once in LDS as bf16 hi/lo, XOR-swizzled; B from
// pre-transposed global bf16 tables Wt[n][128] (L2-resident).
// Fragment layout (16x16x32): A: lane l elem j = A[l&15][8*(l>>4)+j];
//                             B: lane l elem j = B[8*(l>>4)+j][l&15];
//                             D: lane l reg  j = D[4*(l>>4)+j][l&15]  (m89).
// DEG role blocks do a fire-and-forget (non-returning) degree histogram —
// no return path, so they are far cheaper than the old returning-rank pass.
template <int BN, bool DEG>
__global__ __launch_bounds__(256) void mfma_gemm_kernel(
        const float* __restrict__ X,
        const unsigned short* __restrict__ Wth,
        const unsigned short* __restrict__ Wtl,
        unsigned short* __restrict__ H, int M,
        const int* __restrict__ dst, int* __restrict__ deg) {
    __shared__ unsigned short Ah[64 * 128];
    __shared__ unsigned short Al[64 * 128];

    const int bid = blockIdx.x;
    if constexpr (DEG) {
        if (bid >= GB) {
            int e0 = ((bid - GB) * 256 + threadIdx.x) * 4;
            if (e0 < NE) {       // NE % 4 == 0
                int4 d = *reinterpret_cast<const int4*>(dst + e0);
                atomicAdd(&deg[d.x], 1);
                atomicAdd(&deg[d.y], 1);
                atomicAdd(&deg[d.z], 1);
                atomicAdd(&deg[d.w], 1);
            }
            return;
        }
    }

    const int tid = threadIdx.x;
    const int rb  = bid * 64;

    // ---- stage X[rb..rb+64) -> Ah/Al (bf16 split, swizzled) ----
    {
        const float4* Xv = reinterpret_cast<const float4*>(X);
        char* AhB = reinterpret_cast<char*>(Ah);
        char* AlB = reinterpret_cast<char*>(Al);
        for (int i = tid; i < 64 * 32; i += 256) {
            int r = i >> 5, c4 = i & 31;               // col = 4*c4
            float4 v = make_float4(0.f, 0.f, 0.f, 0.f);
            if (rb + r < M) v = Xv[(size_t)(rb + r) * 32 + c4];
            ushort4 hi, lo;
            split_bf16(v.x, hi.x, lo.x);
            split_bf16(v.y, hi.y, lo.y);
            split_bf16(v.z, hi.z, lo.z);
            split_bf16(v.w, hi.w, lo.w);
            int b = (c4 * 8) ^ ((r & 7) << 4);         // in-row byte, 8B-aligned
            *reinterpret_cast<ushort4*>(AhB + r * 256 + b) = hi;
            *reinterpret_cast<ushort4*>(AlB + r * 256 + b) = lo;
        }
    }
    __syncthreads();

    const int lane = tid & 63;
    const int wv   = tid >> 6;
    constexpr int CT = BN / 64;            // col-tiles per wave (2 for 128, 1 for 64)
    const int wc0  = wv * (BN / 4);        // wave col base
    const int lr   = lane & 15;
    const int lg   = lane >> 4;

    f32x4 acc[4][CT];
#pragma unroll
    for (int rt = 0; rt < 4; rt++)
#pragma unroll
        for (int ct = 0; ct < CT; ct++)
            acc[rt][ct] = (f32x4){0.f, 0.f, 0.f, 0.f};

    const char* AhB = reinterpret_cast<const char*>(Ah);
    const char* AlB = reinterpret_cast<const char*>(Al);

#pragma unroll
    for (int k0 = 0; k0 < 128; k0 += 32) {
        bf16x8 ah[4], al[4];
#pragma unroll
        for (int rt = 0; rt < 4; rt++) {
            int row = rt * 16 + lr;
            int inb = (k0 * 2 + lg * 16) ^ ((row & 7) << 4);
            ah[rt] = *reinterpret_cast<const bf16x8*>(AhB + row * 256 + inb);
            al[rt] = *reinterpret_cast<const bf16x8*>(AlB + row * 256 + inb);
        }
#pragma unroll
        for (int ct = 0; ct < CT; ct++) {
            int n = wc0 + ct * 16 + lr;
            int off = n * 128 + k0 + lg * 8;
            bf16x8 bh = *reinterpret_cast<const bf16x8*>(Wth + off);
            bf16x8 bl = *reinterpret_cast<const bf16x8*>(Wtl + off);
#pragma unroll
            for (int rt = 0; rt < 4; rt++) {
                acc[rt][ct] = __builtin_amdgcn_mfma_f32_16x16x32_bf16(ah[rt], bh, acc[rt][ct], 0, 0, 0);
                acc[rt][ct] = __builtin_amdgcn_mfma_f32_16x16x32_bf16(ah[rt], bl, acc[rt][ct], 0, 0, 0);
                acc[rt][ct] = __builtin_amdgcn_mfma_f32_16x16x32_bf16(al[rt], bh, acc[rt][ct], 0, 0, 0);
            }
        }
    }

#pragma unroll
    for (int rt = 0; rt < 4; rt++)
#pragma unroll
        for (int ct = 0; ct < CT; ct++) {
            int col = wc0 + ct * 16 + lr;
#pragma unroll
            for (int j = 0; j < 4; j++) {
                int row = rb + rt * 16 + lg * 4 + j;
                if (row < M) H[(size_t)row * BN + col] = f_to_bfu(acc[rt][ct][j]);
            }
        }
}

// ---------- single-launch scan: deg -> rowptr, cursor, dinv ----------
// Block b redundantly re-sums deg[0 .. b*1024) (L2-resident, <=200 KB for the
// last block) to get its global offset, then block-scans its own 1024-tile.
// Replaces the old reduce + scan_tops + scan_fill (3 launches).
__global__ __launch_bounds__(256) void scan_kernel(const int* __restrict__ deg,
                                                   int* __restrict__ rowptr,
                                                   int* __restrict__ cursor,
                                                   float* __restrict__ dinv, int n) {
    __shared__ int wred[4];
    __shared__ int wsum[4];
    __shared__ int woff[4];
    const int tid = threadIdx.x, lane = tid & 63, wid = tid >> 6;
    const int b = blockIdx.x;

    // ---- prior-prefix sum over deg[0, b*1024) ----
    const int4* deg4 = reinterpret_cast<const int4*>(deg);
    int s = 0;
    for (int i = tid; i < b * 256; i += 256) {
        int4 v = deg4[i];
        s += v.x + v.y + v.z + v.w;
    }
#pragma unroll
    for (int off = 32; off >= 1; off >>= 1) s += __shfl_xor(s, off);
    if (lane == 0) wred[wid] = s;

    // ---- own tile scan ----
    int idx = b * SCAN_B + tid * 4;
    int v0 = (idx + 0 < n) ? deg[idx + 0] : 0;
    int v1 = (idx + 1 < n) ? deg[idx + 1] : 0;
    int v2 = (idx + 2 < n) ? deg[idx + 2] : 0;
    int v3 = (idx + 3 < n) ? deg[idx + 3] : 0;
    int local = v0 + v1 + v2 + v3;
    int incl = local;
#pragma unroll
    for (int off = 1; off < 64; off <<= 1) {
        int t = __shfl_up(incl, off, 64);
        if (lane >= off) incl += t;
    }
    if (lane == 63) wsum[wid] = incl;
    __syncthreads();
    if (tid == 0) {
        int acc = wred[0] + wred[1] + wred[2] + wred[3];   // global offset
        for (int w = 0; w < 4; w++) { woff[w] = acc; acc += wsum[w]; }
    }
    __syncthreads();
    int p = woff[wid] + (incl - local);
    int v[4] = {v0, v1, v2, v3};
#pragma unroll
    for (int j = 0; j < 4; j++) {
        int t = idx + j;
        if (t <= n) rowptr[t] = p;          // includes rowptr[n] = total
        if (t < n) {
            cursor[t] = p;
            dinv[t] = rsqrtf((float)v[j] + 1.0f);
        }
        p += v[j];
    }
}

// ---------- place: counting-sort scatter with returning cursor atomics ----------
__global__ __launch_bounds__(256, 8) void place_kernel(const int* __restrict__ src,
                                                       const int* __restrict__ dst,
                                                       int* __restrict__ cursor,
                                                       unsigned short* __restrict__ srcs) {
    int e0 = (blockIdx.x * 256 + threadIdx.x) * 4;
    if (e0 >= NE) return;   // NE % 4 == 0
    int4 d = *reinterpret_cast<const int4*>(dst + e0);
    int4 s = *reinterpret_cast<const int4*>(src + e0);
    int r0 = atomicAdd(&cursor[d.x], 1);
    int r1 = atomicAdd(&cursor[d.y], 1);
    int r2 = atomicAdd(&cursor[d.z], 1);
    int r3 = atomicAdd(&cursor[d.w], 1);
    srcs[r0] = (unsigned short)s.x;
    srcs[r1] = (unsigned short)s.y;
    srcs[r2] = (unsigned short)s.z;
    srcs[r3] = (unsigned short)s.w;
}

// ---------- fused gather-aggregate + self-loop + bias (+relu) ----------
// Wave per node; LPR = NW/8 lanes cooperate on one source row (16 B bf16x8
// per lane), so one wave processes 64/LPR rows per load issue. Inactive
// lanes carry sv=0/wv=0 so tail rows need no guard (w=0 kills the term,
// row 0 is always valid memory). Partial sums per lane-group are combined
// once per node with a shfl_xor butterfly.
template <int NW, bool RELU>
__global__ __launch_bounds__(256) void gather_kernel(const int* __restrict__ rowptr,
                                                     const unsigned short* __restrict__ srcs,
                                                     const float* __restrict__ dinv,
                                                     const unsigned short* __restrict__ h,
                                                     const float* __restrict__ b,
                                                     float* __restrict__ out, int M) {
    constexpr int LPR = NW / 8;        // lanes per source row (16 / 8)
    constexpr int RPW = 64 / LPR;      // rows per wave-step   (4  / 8)
    const int lane = threadIdx.x & 63;
    const int wid  = threadIdx.x >> 6;
    const int t    = blockIdx.x * 4 + wid;
    if (t >= M) return;
    const int sl = lane % LPR;         // column slice: cols [sl*8, sl*8+8)
    const int sr = lane / LPR;         // sub-row within wave-step

    float acc[8];
#pragma unroll
    for (int c = 0; c < 8; c++) acc[c] = 0.f;

    const int beg = rowptr[t], end = rowptr[t + 1];
    for (int eb = beg; eb < end; eb += 64) {
        const int rem = end - eb;
        int   sv = 0;
        float wv = 0.f;
        if (lane < rem) { sv = (int)srcs[eb + lane]; wv = dinv[sv]; }
        const int m = rem < 64 ? rem : 64;
        for (int j = 0; j < m; j += RPW) {
            int   s = __shfl(sv, j + sr);
            float w = __shfl(wv, j + sr);
            bf16x8 hv = *reinterpret_cast<const bf16x8*>(h + (size_t)s * NW + sl * 8);
#pragma unroll
            for (int c = 0; c < 8; c++)
                acc[c] += w * bfu_to_f((unsigned short)hv[c]);
        }
    }

    // combine the 64/LPR sub-row partials (butterfly -> all lanes hold total)
#pragma unroll
    for (int off = LPR; off < 64; off <<= 1)
#pragma unroll
        for (int c = 0; c < 8; c++) acc[c] += __shfl_xor(acc[c], off);

    if (sr == 0) {
        const float di = dinv[t];
        bf16x8 own = *reinterpret_cast<const bf16x8*>(h + (size_t)t * NW + sl * 8);
        float4 b0 = *reinterpret_cast<const float4*>(b + sl * 8);
        float4 b1 = *reinterpret_cast<const float4*>(b + sl * 8 + 4);
        float v[8];
#pragma unroll
        for (int c = 0; c < 8; c++) {
            float bc = (c < 4) ? (&b0.x)[c] : (&b1.x)[c - 4];
            v[c] = acc[c] * di + bfu_to_f((unsigned short)own[c]) * di * di + bc;
            if (RELU) v[c] = fmaxf(v[c], 0.f);
        }
        float* op = out + (size_t)t * NW + sl * 8;
        *reinterpret_cast<float4*>(op)     = make_float4(v[0], v[1], v[2], v[3]);
        *reinterpret_cast<float4*>(op + 4) = make_float4(v[4], v[5], v[6], v[7]);
    }
}

extern "C" void kernel_launch(void* const* d_in, const int* in_sizes, int n_in,
                              void* d_out, int out_size, void* d_ws, size_t ws_size,
                              hipStream_t stream) {
    const float* x  = (const float*)d_in[0];
    const int*   ei = (const int*)d_in[1];
    const float* W1 = (const float*)d_in[2];
    const float* b1 = (const float*)d_in[3];
    const float* W2 = (const float*)d_in[4];
    const float* b2 = (const float*)d_in[5];

    float* out_h2 = (float*)d_out;                 // [NN x 64]
    float* out_h1 = out_h2 + (size_t)NN * 64;      // [NN x 128]

    const int* src = ei;
    const int* dst = ei + NE;

    // ws layout (4B words), ~16 MB of workspace:
    int*   wsw    = (int*)d_ws;
    int*   deg    = wsw;                        // NN2 = 50048
    int*   rowptr = wsw + 50048;                // 50064
    int*   cursor = wsw + 100112;               // NN2
    float* dinv   = (float*)(wsw + 150160);     // NN2
    unsigned short* srcs = (unsigned short*)(wsw + 200208);   // u16 [NE] = 400000 words
    unsigned short* T    = (unsigned short*)(wsw + 600208);   // bf16 [NN x 128]
    unsigned short* wt1h = (unsigned short*)(wsw + 3800208);  // [128x128]
    unsigned short* wt1l = (unsigned short*)(wsw + 3808400);  // [128x128]
    unsigned short* wt2h = (unsigned short*)(wsw + 3816592);  // [64x128]
    unsigned short* wt2l = (unsigned short*)(wsw + 3820688);  // [64x128]

    // ----- W split/transpose prep + deg zeroing (one launch) -----
    wprep_kernel<<<145, 256, 0, stream>>>(W1, W2, wt1h, wt1l, wt2h, wt2l, deg);

    // ----- fused: layer-1 MFMA GEMM + degree histogram (non-returning atomics) -----
    mfma_gemm_kernel<128, true><<<GB + E4_BLOCKS, 256, 0, stream>>>(
        x, wt1h, wt1l, T, NN, dst, deg);

    // ----- CSR: single-launch scan -> place (cursor counting-sort) -----
    scan_kernel<<<NB, 256, 0, stream>>>(deg, rowptr, cursor, dinv, NN);
    place_kernel<<<E4_BLOCKS, 256, 0, stream>>>(src, dst, cursor, srcs);

    const int aB = (NN + 3) / 4;

    // ----- layer 1 gather -----
    gather_kernel<128, true><<<aB, 256, 0, stream>>>(rowptr, srcs, dinv, T,
                                                     b1, out_h1, NN);
    // ----- layer 2 -----
    mfma_gemm_kernel<64, false><<<GB, 256, 0, stream>>>(
        out_h1, wt2h, wt2l, T, NN, nullptr, nullptr);
    gather_kernel<64, false><<<aB, 256, 0, stream>>>(rowptr, srcs, dinv, T,
                                                     b2, out_h2, NN);
}

// Round 6
// 256.052 us; speedup vs baseline: 1.0111x; 1.0111x over previous
//
#include <hip/hip_runtime.h>
#include <hip/hip_bf16.h>

constexpr int NN  = 50000;
constexpr int NN2 = 50048;
constexpr int NE  = 800000;
constexpr int SCAN_B = 1024;
constexpr int NB = (NN + SCAN_B - 1) / SCAN_B;    // 49 scan blocks
constexpr int GB = (NN + 63) / 64;                // 782 gemm blocks (64 rows each)
constexpr int RANK_BLOCKS = (NE + 255) / 256;     // 3125 (place kernel)
constexpr int RANK4_BLOCKS = (NE / 4 + 255) / 256; // 782 (rank role, 4 edges/thread)
constexpr int ZB = (8 * NN2 / 4 + 255) / 256;     // 391 cnt-zero blocks in wprep

typedef short bf16x8 __attribute__((ext_vector_type(8)));
typedef float f32x4  __attribute__((ext_vector_type(4)));

__device__ __forceinline__ float bfu_to_f(unsigned int u16) {
    return __uint_as_float(u16 << 16);
}
__device__ __forceinline__ unsigned short f_to_bfu(float f) {
    unsigned int u = __float_as_uint(f);
    return (unsigned short)((u + 0x7fffu + ((u >> 16) & 1u)) >> 16);
}
__device__ __forceinline__ void split_bf16(float v, unsigned short& h, unsigned short& l) {
    h = f_to_bfu(v);
    l = f_to_bfu(v - bfu_to_f(h));
}

// real XCD id of the executing wave (0..7 on MI355X) — wave-uniform SGPR read
__device__ __forceinline__ int xcc_id() {
    int x;
    asm volatile("s_getreg_b32 %0, hwreg(HW_REG_XCC_ID, 0, 4)" : "=s"(x));
    return x & 7;
}

// ---------- W prep (transposed bf16 hi/lo tables Wt[n][k]) + cnt zeroing ----------
// blocks [0,96): W split/transpose; blocks [96,96+ZB): zero cnt[8*NN2]
__global__ __launch_bounds__(256) void wprep_kernel(
        const float* __restrict__ W1, const float* __restrict__ W2,
        unsigned short* __restrict__ wt1h, unsigned short* __restrict__ wt1l,
        unsigned short* __restrict__ wt2h, unsigned short* __restrict__ wt2l,
        int* __restrict__ cnt) {
    const int bid = blockIdx.x;
    if (bid >= 96) {
        int i = ((bid - 96) * 256 + threadIdx.x) * 4;
        if (i < 8 * NN2) *reinterpret_cast<int4*>(cnt + i) = make_int4(0, 0, 0, 0);
        return;
    }
    int i = bid * 256 + threadIdx.x;
    if (i < 128 * 128) {
        int n = i >> 7, k = i & 127;
        unsigned short h, l;
        split_bf16(W1[k * 128 + n], h, l);
        wt1h[i] = h; wt1l[i] = l;
    }
    i -= 128 * 128;
    if (i >= 0 && i < 64 * 128) {
        int n = i >> 7, k = i & 127;
        unsigned short h, l;
        split_bf16(W2[k * 64 + n], h, l);
        wt2h[i] = h; wt2l[i] = l;
    }
}

// ---------- MFMA GEMM (bf16 split, fp32-accurate) + optional fused rank role ----------
// C[M x BN] = X[M x 128] @ W[128 x BN], H stored bf16 row-major stride BN.
// A-tile (64 x 128) staged once in LDS as bf16 hi/lo, XOR-swizzled; B from
// pre-transposed global bf16 tables Wt[n][128] (L2-resident).
// Fragment layout (16x16x32): A: lane l elem j = A[l&15][8*(l>>4)+j];
//                             B: lane l elem j = B[8*(l>>4)+j][l&15];
//                             D: lane l reg  j = D[4*(l>>4)+j][l&15]  (m89).
// RANK role: 8-XCD-replica returning atomics, overlapped under the GEMM waves
// (this overlap + contention spreading is load-bearing: round-4's single-array
// standalone variant regressed 32 µs).
template <int BN, bool RANK>
__global__ __launch_bounds__(256) void mfma_gemm_kernel(
        const float* __restrict__ X,
        const unsigned short* __restrict__ Wth,
        const unsigned short* __restrict__ Wtl,
        unsigned short* __restrict__ H, int M,
        const int* __restrict__ dst, int* __restrict__ cnt, int* __restrict__ pos) {
    __shared__ unsigned short Ah[64 * 128];
    __shared__ unsigned short Al[64 * 128];

    const int bid = blockIdx.x;
    if constexpr (RANK) {
        if (bid >= GB) {
            // ---- rank role: pos[e] = rank within (XCD-replica, dst) bucket ----
            int e0 = ((bid - GB) * 256 + threadIdx.x) * 4;
            if (e0 < NE) {       // NE % 4 == 0
                const int rep = xcc_id();
                const int repb = rep << 24;
                int* c = cnt + rep * NN2;
                int4 d = *reinterpret_cast<const int4*>(dst + e0);
                int r0 = __hip_atomic_fetch_add(&c[d.x], 1, __ATOMIC_RELAXED, __HIP_MEMORY_SCOPE_WORKGROUP);
                int r1 = __hip_atomic_fetch_add(&c[d.y], 1, __ATOMIC_RELAXED, __HIP_MEMORY_SCOPE_WORKGROUP);
                int r2 = __hip_atomic_fetch_add(&c[d.z], 1, __ATOMIC_RELAXED, __HIP_MEMORY_SCOPE_WORKGROUP);
                int r3 = __hip_atomic_fetch_add(&c[d.w], 1, __ATOMIC_RELAXED, __HIP_MEMORY_SCOPE_WORKGROUP);
                *reinterpret_cast<int4*>(pos + e0) =
                    make_int4(r0 | repb, r1 | repb, r2 | repb, r3 | repb);
            }
            return;
        }
    }

    const int tid = threadIdx.x;
    const int rb  = bid * 64;

    // ---- stage X[rb..rb+64) -> Ah/Al (bf16 split, swizzled) ----
    {
        const float4* Xv = reinterpret_cast<const float4*>(X);
        char* AhB = reinterpret_cast<char*>(Ah);
        char* AlB = reinterpret_cast<char*>(Al);
        for (int i = tid; i < 64 * 32; i += 256) {
            int r = i >> 5, c4 = i & 31;               // col = 4*c4
            float4 v = make_float4(0.f, 0.f, 0.f, 0.f);
            if (rb + r < M) v = Xv[(size_t)(rb + r) * 32 + c4];
            ushort4 hi, lo;
            split_bf16(v.x, hi.x, lo.x);
            split_bf16(v.y, hi.y, lo.y);
            split_bf16(v.z, hi.z, lo.z);
            split_bf16(v.w, hi.w, lo.w);
            int b = (c4 * 8) ^ ((r & 7) << 4);         // in-row byte, 8B-aligned
            *reinterpret_cast<ushort4*>(AhB + r * 256 + b) = hi;
            *reinterpret_cast<ushort4*>(AlB + r * 256 + b) = lo;
        }
    }
    __syncthreads();

    const int lane = tid & 63;
    const int wv   = tid >> 6;
    constexpr int CT = BN / 64;            // col-tiles per wave (2 for 128, 1 for 64)
    const int wc0  = wv * (BN / 4);        // wave col base
    const int lr   = lane & 15;
    const int lg   = lane >> 4;

    f32x4 acc[4][CT];
#pragma unroll
    for (int rt = 0; rt < 4; rt++)
#pragma unroll
        for (int ct = 0; ct < CT; ct++)
            acc[rt][ct] = (f32x4){0.f, 0.f, 0.f, 0.f};

    const char* AhB = reinterpret_cast<const char*>(Ah);
    const char* AlB = reinterpret_cast<const char*>(Al);

#pragma unroll
    for (int k0 = 0; k0 < 128; k0 += 32) {
        bf16x8 ah[4], al[4];
#pragma unroll
        for (int rt = 0; rt < 4; rt++) {
            int row = rt * 16 + lr;
            int inb = (k0 * 2 + lg * 16) ^ ((row & 7) << 4);
            ah[rt] = *reinterpret_cast<const bf16x8*>(AhB + row * 256 + inb);
            al[rt] = *reinterpret_cast<const bf16x8*>(AlB + row * 256 + inb);
        }
#pragma unroll
        for (int ct = 0; ct < CT; ct++) {
            int n = wc0 + ct * 16 + lr;
            int off = n * 128 + k0 + lg * 8;
            bf16x8 bh = *reinterpret_cast<const bf16x8*>(Wth + off);
            bf16x8 bl = *reinterpret_cast<const bf16x8*>(Wtl + off);
#pragma unroll
            for (int rt = 0; rt < 4; rt++) {
                acc[rt][ct] = __builtin_amdgcn_mfma_f32_16x16x32_bf16(ah[rt], bh, acc[rt][ct], 0, 0, 0);
                acc[rt][ct] = __builtin_amdgcn_mfma_f32_16x16x32_bf16(ah[rt], bl, acc[rt][ct], 0, 0, 0);
                acc[rt][ct] = __builtin_amdgcn_mfma_f32_16x16x32_bf16(al[rt], bh, acc[rt][ct], 0, 0, 0);
            }
        }
    }

#pragma unroll
    for (int rt = 0; rt < 4; rt++)
#pragma unroll
        for (int ct = 0; ct < CT; ct++) {
            int col = wc0 + ct * 16 + lr;
#pragma unroll
            for (int j = 0; j < 4; j++) {
                int row = rb + rt * 16 + lg * 4 + j;
                if (row < M) H[(size_t)row * BN + col] = f_to_bfu(acc[rt][ct][j]);
            }
        }
}

// ---------- single-launch scan: cnt (8 replicas) -> roff, rowptr, dinv ----------
// Block b redundantly re-sums cnt[r][0 .. b*1024) over all 8 replicas to get
// its global offset (L2-resident, <=1.6 MB for the last block), then scans
// its own 1024-node tile. Replaces reduce + scan_tops + scan_fill.
__global__ __launch_bounds__(256) void scan_kernel(const int* __restrict__ cnt,
                                                   int* __restrict__ roff,
                                                   int* __restrict__ rowptr,
                                                   float* __restrict__ dinv, int n) {
    __shared__ int wred[4];
    __shared__ int wsum[4];
    __shared__ int woff[4];
    const int tid = threadIdx.x, lane = tid & 63, wid = tid >> 6;
    const int b = blockIdx.x;

    // ---- prior-prefix sum over all replicas, nodes [0, b*1024) ----
    int s = 0;
#pragma unroll
    for (int r = 0; r < 8; r++) {
        const int4* c4 = reinterpret_cast<const int4*>(cnt + r * NN2);
        for (int i = tid; i < b * 256; i += 256) {
            int4 v = c4[i];
            s += v.x + v.y + v.z + v.w;
        }
    }
#pragma unroll
    for (int off = 32; off >= 1; off >>= 1) s += __shfl_xor(s, off);
    if (lane == 0) wred[wid] = s;

    // ---- own tile: per-node replica prefix (roff) + degree ----
    int idx = b * SCAN_B + tid * 4;
    int v[4];
#pragma unroll
    for (int j = 0; j < 4; j++) {
        int t = idx + j;
        int acc = 0;
        if (t < n) {
#pragma unroll
            for (int r = 0; r < 8; r++) {
                roff[r * NN2 + t] = acc;
                acc += cnt[r * NN2 + t];
            }
            dinv[t] = rsqrtf((float)acc + 1.0f);
        }
        v[j] = acc;
    }
    int local = v[0] + v[1] + v[2] + v[3];
    int incl = local;
#pragma unroll
    for (int off = 1; off < 64; off <<= 1) {
        int t = __shfl_up(incl, off, 64);
        if (lane >= off) incl += t;
    }
    if (lane == 63) wsum[wid] = incl;
    __syncthreads();
    if (tid == 0) {
        int acc = wred[0] + wred[1] + wred[2] + wred[3];   // global offset
        for (int w = 0; w < 4; w++) { woff[w] = acc; acc += wsum[w]; }
    }
    __syncthreads();
    int p = woff[wid] + (incl - local);
#pragma unroll
    for (int j = 0; j < 4; j++) {
        int t = idx + j;
        if (t <= n) rowptr[t] = p;          // includes rowptr[n] = total
        p += v[j];
    }
}

// ---------- place: srcs[rowptr[t] + roff[rep][t] + rank] = src[e] (atomic-free) ----------
__global__ __launch_bounds__(256) void place_kernel(const int* __restrict__ src,
                                                    const int* __restrict__ dst,
                                                    const int* __restrict__ rowptr,
                                                    const int* __restrict__ roff,
                                                    const int* __restrict__ pos,
                                                    unsigned short* __restrict__ srcs,
                                                    int E) {
    int e = blockIdx.x * 256 + threadIdx.x;
    if (e >= E) return;
    int t = dst[e];
    int pr = pos[e];
    int rep = pr >> 24;                 // replica = XCD that ranked this edge
    srcs[rowptr[t] + roff[rep * NN2 + t] + (pr & 0xffffff)] = (unsigned short)src[e];
}

// ---------- fused gather-aggregate + self-loop + bias (+relu) ----------
// Wave per node; LPR = NW/8 lanes cooperate on one source row (16 B bf16x8
// per lane), so one wave processes 64/LPR rows per load issue. Inactive
// lanes carry sv=0/wv=0 so tail rows need no guard (w=0 kills the term,
// row 0 is always valid memory). Partial sums per lane-group are combined
// once per node with a shfl_xor butterfly.
template <int NW, bool RELU>
__global__ __launch_bounds__(256) void gather_kernel(const int* __restrict__ rowptr,
                                                     const unsigned short* __restrict__ srcs,
                                                     const float* __restrict__ dinv,
                                                     const unsigned short* __restrict__ h,
                                                     const float* __restrict__ b,
                                                     float* __restrict__ out, int M) {
    constexpr int LPR = NW / 8;        // lanes per source row (16 / 8)
    constexpr int RPW = 64 / LPR;      // rows per wave-step   (4  / 8)
    const int lane = threadIdx.x & 63;
    const int wid  = threadIdx.x >> 6;
    const int t    = blockIdx.x * 4 + wid;
    if (t >= M) return;
    const int sl = lane % LPR;         // column slice: cols [sl*8, sl*8+8)
    const int sr = lane / LPR;         // sub-row within wave-step

    float acc[8];
#pragma unroll
    for (int c = 0; c < 8; c++) acc[c] = 0.f;

    const int beg = rowptr[t], end = rowptr[t + 1];
    for (int eb = beg; eb < end; eb += 64) {
        const int rem = end - eb;
        int   sv = 0;
        float wv = 0.f;
        if (lane < rem) { sv = (int)srcs[eb + lane]; wv = dinv[sv]; }
        const int m = rem < 64 ? rem : 64;
        for (int j = 0; j < m; j += RPW) {
            int   s = __shfl(sv, j + sr);
            float w = __shfl(wv, j + sr);
            bf16x8 hv = *reinterpret_cast<const bf16x8*>(h + (size_t)s * NW + sl * 8);
#pragma unroll
            for (int c = 0; c < 8; c++)
                acc[c] += w * bfu_to_f((unsigned short)hv[c]);
        }
    }

    // combine the 64/LPR sub-row partials (butterfly -> all lanes hold total)
#pragma unroll
    for (int off = LPR; off < 64; off <<= 1)
#pragma unroll
        for (int c = 0; c < 8; c++) acc[c] += __shfl_xor(acc[c], off);

    if (sr == 0) {
        const float di = dinv[t];
        bf16x8 own = *reinterpret_cast<const bf16x8*>(h + (size_t)t * NW + sl * 8);
        float4 b0 = *reinterpret_cast<const float4*>(b + sl * 8);
        float4 b1 = *reinterpret_cast<const float4*>(b + sl * 8 + 4);
        float v[8];
#pragma unroll
        for (int c = 0; c < 8; c++) {
            float bc = (c < 4) ? (&b0.x)[c] : (&b1.x)[c - 4];
            v[c] = acc[c] * di + bfu_to_f((unsigned short)own[c]) * di * di + bc;
            if (RELU) v[c] = fmaxf(v[c], 0.f);
        }
        float* op = out + (size_t)t * NW + sl * 8;
        *reinterpret_cast<float4*>(op)     = make_float4(v[0], v[1], v[2], v[3]);
        *reinterpret_cast<float4*>(op + 4) = make_float4(v[4], v[5], v[6], v[7]);
    }
}

extern "C" void kernel_launch(void* const* d_in, const int* in_sizes, int n_in,
                              void* d_out, int out_size, void* d_ws, size_t ws_size,
                              hipStream_t stream) {
    const float* x  = (const float*)d_in[0];
    const int*   ei = (const int*)d_in[1];
    const float* W1 = (const float*)d_in[2];
    const float* b1 = (const float*)d_in[3];
    const float* W2 = (const float*)d_in[4];
    const float* b2 = (const float*)d_in[5];

    float* out_h2 = (float*)d_out;                 // [NN x 64]
    float* out_h1 = out_h2 + (size_t)NN * 64;      // [NN x 128]

    const int* src = ei;
    const int* dst = ei + NE;

    // ws layout (4B words):
    int*   wsw    = (int*)d_ws;
    int*   cnt    = wsw;                        // 8*NN2 = 400384
    int*   roff   = wsw + 400384;               // 8*NN2 = 400384
    int*   pos    = wsw + 800768;               // NE = 800000
    int*   rowptr = wsw + 1600768;              // 50064
    float* dinv   = (float*)(wsw + 1650832);    // NN2
    unsigned short* srcs = (unsigned short*)(wsw + 1700880);  // u16 [NE] = 400000 words
    unsigned short* T    = (unsigned short*)(wsw + 2100880);  // bf16 [NN x 128]
    unsigned short* wt1h = (unsigned short*)(wsw + 5300880);  // [128x128]
    unsigned short* wt1l = (unsigned short*)(wsw + 5309072);  // [128x128]
    unsigned short* wt2h = (unsigned short*)(wsw + 5317264);  // [64x128]
    unsigned short* wt2l = (unsigned short*)(wsw + 5321360);  // [64x128]

    // ----- W split/transpose prep + cnt zeroing (one launch, no memset) -----
    wprep_kernel<<<96 + ZB, 256, 0, stream>>>(W1, W2, wt1h, wt1l, wt2h, wt2l, cnt);

    // ----- fused: layer-1 MFMA GEMM + 8-replica rank histogram (overlapped) -----
    mfma_gemm_kernel<128, true><<<GB + RANK4_BLOCKS, 256, 0, stream>>>(
        x, wt1h, wt1l, T, NN, dst, cnt, pos);

    // ----- CSR: single-launch scan -> place (atomic-free) -----
    scan_kernel<<<NB, 256, 0, stream>>>(cnt, roff, rowptr, dinv, NN);
    place_kernel<<<RANK_BLOCKS, 256, 0, stream>>>(src, dst, rowptr, roff, pos, srcs, NE);

    const int aB = (NN + 3) / 4;

    // ----- layer 1 gather -----
    gather_kernel<128, true><<<aB, 256, 0, stream>>>(rowptr, srcs, dinv, T,
                                                     b1, out_h1, NN);
    // ----- layer 2 -----
    mfma_gemm_kernel<64, false><<<GB, 256, 0, stream>>>(
        out_h1, wt2h, wt2l, T, NN, nullptr, nullptr, nullptr);
    gather_kernel<64, false><<<aB, 256, 0, stream>>>(rowptr, srcs, dinv, T,
                                                     b2, out_h2, NN);
}

// Round 7
// 222.735 us; speedup vs baseline: 1.1623x; 1.1496x over previous
//
#include <hip/hip_runtime.h>
#include <hip/hip_bf16.h>

constexpr int NN  = 50000;
constexpr int NN2 = 50048;
constexpr int NE  = 800000;
constexpr int SCAN_B = 1024;
constexpr int NB = (NN + SCAN_B - 1) / SCAN_B;    // 49 scan blocks
constexpr int GB = (NN + 63) / 64;                // 782 gemm blocks (64 rows each)
constexpr int RANK_BLOCKS = (NE + 255) / 256;     // 3125 (place kernel)
constexpr int RANK4_BLOCKS = (NE / 4 + 255) / 256; // 782 (rank role, 4 edges/thread)
constexpr int ZB = (8 * NN2 / 4 + 255) / 256;     // 391 cnt-zero blocks in wprep

typedef short bf16x8 __attribute__((ext_vector_type(8)));
typedef float f32x4  __attribute__((ext_vector_type(4)));

__device__ __forceinline__ float bfu_to_f(unsigned int u16) {
    return __uint_as_float(u16 << 16);
}
__device__ __forceinline__ unsigned short f_to_bfu(float f) {
    unsigned int u = __float_as_uint(f);
    return (unsigned short)((u + 0x7fffu + ((u >> 16) & 1u)) >> 16);
}
__device__ __forceinline__ void split_bf16(float v, unsigned short& h, unsigned short& l) {
    h = f_to_bfu(v);
    l = f_to_bfu(v - bfu_to_f(h));
}

// real XCD id of the executing wave (0..7 on MI355X) — wave-uniform SGPR read
__device__ __forceinline__ int xcc_id() {
    int x;
    asm volatile("s_getreg_b32 %0, hwreg(HW_REG_XCC_ID, 0, 4)" : "=s"(x));
    return x & 7;
}

// ---------- W prep (transposed bf16 hi/lo tables Wt[n][k]) + cnt zeroing ----------
// blocks [0,96): W split/transpose; blocks [96,96+ZB): zero cnt[8*NN2]
__global__ __launch_bounds__(256) void wprep_kernel(
        const float* __restrict__ W1, const float* __restrict__ W2,
        unsigned short* __restrict__ wt1h, unsigned short* __restrict__ wt1l,
        unsigned short* __restrict__ wt2h, unsigned short* __restrict__ wt2l,
        int* __restrict__ cnt) {
    const int bid = blockIdx.x;
    if (bid >= 96) {
        int i = ((bid - 96) * 256 + threadIdx.x) * 4;
        if (i < 8 * NN2) *reinterpret_cast<int4*>(cnt + i) = make_int4(0, 0, 0, 0);
        return;
    }
    int i = bid * 256 + threadIdx.x;
    if (i < 128 * 128) {
        int n = i >> 7, k = i & 127;
        unsigned short h, l;
        split_bf16(W1[k * 128 + n], h, l);
        wt1h[i] = h; wt1l[i] = l;
    }
    i -= 128 * 128;
    if (i >= 0 && i < 64 * 128) {
        int n = i >> 7, k = i & 127;
        unsigned short h, l;
        split_bf16(W2[k * 64 + n], h, l);
        wt2h[i] = h; wt2l[i] = l;
    }
}

// ---------- MFMA GEMM (bf16 split, fp32-accurate) + optional fused rank role ----------
// C[M x BN] = X[M x 128] @ W[128 x BN], H stored bf16 row-major stride BN.
// A-tile (64 x 128) staged once in LDS as bf16 hi/lo, XOR-swizzled; B from
// pre-transposed global bf16 tables Wt[n][128] (L2-resident).
// Fragment layout (16x16x32): A: lane l elem j = A[l&15][8*(l>>4)+j];
//                             B: lane l elem j = B[8*(l>>4)+j][l&15];
//                             D: lane l reg  j = D[4*(l>>4)+j][l&15]  (m89).
// RANK role: 8-XCD-replica returning atomics, overlapped under the GEMM waves
// (overlap + contention spreading is load-bearing: round-4's single-array
// standalone variant regressed 32 µs).
template <int BN, bool RANK>
__global__ __launch_bounds__(256) void mfma_gemm_kernel(
        const float* __restrict__ X,
        const unsigned short* __restrict__ Wth,
        const unsigned short* __restrict__ Wtl,
        unsigned short* __restrict__ H, int M,
        const int* __restrict__ dst, int* __restrict__ cnt, int* __restrict__ pos) {
    __shared__ unsigned short Ah[64 * 128];
    __shared__ unsigned short Al[64 * 128];

    const int bid = blockIdx.x;
    if constexpr (RANK) {
        if (bid >= GB) {
            // ---- rank role: pos[e] = rank within (XCD-replica, dst) bucket ----
            int e0 = ((bid - GB) * 256 + threadIdx.x) * 4;
            if (e0 < NE) {       // NE % 4 == 0
                const int rep = xcc_id();
                const int repb = rep << 24;
                int* c = cnt + rep * NN2;
                int4 d = *reinterpret_cast<const int4*>(dst + e0);
                int r0 = __hip_atomic_fetch_add(&c[d.x], 1, __ATOMIC_RELAXED, __HIP_MEMORY_SCOPE_WORKGROUP);
                int r1 = __hip_atomic_fetch_add(&c[d.y], 1, __ATOMIC_RELAXED, __HIP_MEMORY_SCOPE_WORKGROUP);
                int r2 = __hip_atomic_fetch_add(&c[d.z], 1, __ATOMIC_RELAXED, __HIP_MEMORY_SCOPE_WORKGROUP);
                int r3 = __hip_atomic_fetch_add(&c[d.w], 1, __ATOMIC_RELAXED, __HIP_MEMORY_SCOPE_WORKGROUP);
                *reinterpret_cast<int4*>(pos + e0) =
                    make_int4(r0 | repb, r1 | repb, r2 | repb, r3 | repb);
            }
            return;
        }
    }

    const int tid = threadIdx.x;
    const int rb  = bid * 64;

    // ---- stage X[rb..rb+64) -> Ah/Al (bf16 split, swizzled) ----
    {
        const float4* Xv = reinterpret_cast<const float4*>(X);
        char* AhB = reinterpret_cast<char*>(Ah);
        char* AlB = reinterpret_cast<char*>(Al);
        for (int i = tid; i < 64 * 32; i += 256) {
            int r = i >> 5, c4 = i & 31;               // col = 4*c4
            float4 v = make_float4(0.f, 0.f, 0.f, 0.f);
            if (rb + r < M) v = Xv[(size_t)(rb + r) * 32 + c4];
            ushort4 hi, lo;
            split_bf16(v.x, hi.x, lo.x);
            split_bf16(v.y, hi.y, lo.y);
            split_bf16(v.z, hi.z, lo.z);
            split_bf16(v.w, hi.w, lo.w);
            int b = (c4 * 8) ^ ((r & 7) << 4);         // in-row byte, 8B-aligned
            *reinterpret_cast<ushort4*>(AhB + r * 256 + b) = hi;
            *reinterpret_cast<ushort4*>(AlB + r * 256 + b) = lo;
        }
    }
    __syncthreads();

    const int lane = tid & 63;
    const int wv   = tid >> 6;
    constexpr int CT = BN / 64;            // col-tiles per wave (2 for 128, 1 for 64)
    const int wc0  = wv * (BN / 4);        // wave col base
    const int lr   = lane & 15;
    const int lg   = lane >> 4;

    f32x4 acc[4][CT];
#pragma unroll
    for (int rt = 0; rt < 4; rt++)
#pragma unroll
        for (int ct = 0; ct < CT; ct++)
            acc[rt][ct] = (f32x4){0.f, 0.f, 0.f, 0.f};

    const char* AhB = reinterpret_cast<const char*>(Ah);
    const char* AlB = reinterpret_cast<const char*>(Al);

#pragma unroll
    for (int k0 = 0; k0 < 128; k0 += 32) {
        bf16x8 ah[4], al[4];
#pragma unroll
        for (int rt = 0; rt < 4; rt++) {
            int row = rt * 16 + lr;
            int inb = (k0 * 2 + lg * 16) ^ ((row & 7) << 4);
            ah[rt] = *reinterpret_cast<const bf16x8*>(AhB + row * 256 + inb);
            al[rt] = *reinterpret_cast<const bf16x8*>(AlB + row * 256 + inb);
        }
#pragma unroll
        for (int ct = 0; ct < CT; ct++) {
            int n = wc0 + ct * 16 + lr;
            int off = n * 128 + k0 + lg * 8;
            bf16x8 bh = *reinterpret_cast<const bf16x8*>(Wth + off);
            bf16x8 bl = *reinterpret_cast<const bf16x8*>(Wtl + off);
#pragma unroll
            for (int rt = 0; rt < 4; rt++) {
                acc[rt][ct] = __builtin_amdgcn_mfma_f32_16x16x32_bf16(ah[rt], bh, acc[rt][ct], 0, 0, 0);
                acc[rt][ct] = __builtin_amdgcn_mfma_f32_16x16x32_bf16(ah[rt], bl, acc[rt][ct], 0, 0, 0);
                acc[rt][ct] = __builtin_amdgcn_mfma_f32_16x16x32_bf16(al[rt], bh, acc[rt][ct], 0, 0, 0);
            }
        }
    }

#pragma unroll
    for (int rt = 0; rt < 4; rt++)
#pragma unroll
        for (int ct = 0; ct < CT; ct++) {
            int col = wc0 + ct * 16 + lr;
#pragma unroll
            for (int j = 0; j < 4; j++) {
                int row = rb + rt * 16 + lg * 4 + j;
                if (row < M) H[(size_t)row * BN + col] = f_to_bfu(acc[rt][ct][j]);
            }
        }
}

// ---------- reduce replicas (own tile only): deg, dinv, roff, per-block sums ----------
__global__ __launch_bounds__(256) void reduce_kernel(const int* __restrict__ cnt,
                                                     int* __restrict__ deg,
                                                     int* __restrict__ roff,
                                                     float* __restrict__ dinv,
                                                     int* __restrict__ bsum, int n) {
    __shared__ int wred[4];
    const int tid = threadIdx.x, lane = tid & 63, wid = tid >> 6;
    int t0 = blockIdx.x * SCAN_B + tid * 4;
    int local = 0;
#pragma unroll
    for (int j = 0; j < 4; j++) {
        int t = t0 + j;
        if (t < n) {
            int acc = 0;
#pragma unroll
            for (int r = 0; r < 8; r++) {
                roff[r * NN2 + t] = acc;
                acc += cnt[r * NN2 + t];
            }
            deg[t] = acc;
            dinv[t] = rsqrtf((float)acc + 1.0f);
            local += acc;
        }
    }
#pragma unroll
    for (int off = 32; off >= 1; off >>= 1) local += __shfl_xor(local, off);
    if (lane == 0) wred[wid] = local;
    __syncthreads();
    if (tid == 0) bsum[blockIdx.x] = wred[0] + wred[1] + wred[2] + wred[3];
}

// ---------- fill: per-block scan + inline tops-scan of bsum -> rowptr ----------
// Each block redundantly sums bsum[0..b) in wave 0 (49 ints, L2-hot) — no
// separate scan_tops launch needed.
__global__ __launch_bounds__(256) void fill_kernel(const int* __restrict__ deg,
                                                   const int* __restrict__ bsum,
                                                   int* __restrict__ rowptr, int n) {
    __shared__ int sboff;
    __shared__ int wsum[4];
    __shared__ int woff[4];
    const int tid = threadIdx.x, lane = tid & 63, wid = tid >> 6;
    const int b = blockIdx.x;

    if (wid == 0) {
        int v = (lane < b) ? bsum[lane] : 0;      // NB <= 64
#pragma unroll
        for (int off = 32; off >= 1; off >>= 1) v += __shfl_xor(v, off);
        if (lane == 0) sboff = v;
    }

    int idx = b * SCAN_B + tid * 4;
    int v0 = (idx + 0 < n) ? deg[idx + 0] : 0;
    int v1 = (idx + 1 < n) ? deg[idx + 1] : 0;
    int v2 = (idx + 2 < n) ? deg[idx + 2] : 0;
    int v3 = (idx + 3 < n) ? deg[idx + 3] : 0;
    int local = v0 + v1 + v2 + v3;
    int incl = local;
#pragma unroll
    for (int off = 1; off < 64; off <<= 1) {
        int t = __shfl_up(incl, off, 64);
        if (lane >= off) incl += t;
    }
    if (lane == 63) wsum[wid] = incl;
    __syncthreads();
    if (tid == 0) {
        int acc = sboff;
        for (int w = 0; w < 4; w++) { woff[w] = acc; acc += wsum[w]; }
    }
    __syncthreads();
    int p = woff[wid] + (incl - local);
    int v[4] = {v0, v1, v2, v3};
#pragma unroll
    for (int j = 0; j < 4; j++) {
        int t = idx + j;
        if (t <= n) rowptr[t] = p;                // includes rowptr[n] = total
        p += v[j];
    }
}

// ---------- place: srcs[rowptr[t] + roff[rep][t] + rank] = src[e] (atomic-free) ----------
__global__ __launch_bounds__(256) void place_kernel(const int* __restrict__ src,
                                                    const int* __restrict__ dst,
                                                    const int* __restrict__ rowptr,
                                                    const int* __restrict__ roff,
                                                    const int* __restrict__ pos,
                                                    unsigned short* __restrict__ srcs,
                                                    int E) {
    int e = blockIdx.x * 256 + threadIdx.x;
    if (e >= E) return;
    int t = dst[e];
    int pr = pos[e];
    int rep = pr >> 24;                 // replica = XCD that ranked this edge
    srcs[rowptr[t] + roff[rep * NN2 + t] + (pr & 0xffffff)] = (unsigned short)src[e];
}

// ---------- fused gather-aggregate + self-loop + bias (+relu) ----------
// Wave per node; LPR = NW/8 lanes cooperate on one source row (16 B bf16x8
// per lane), so one wave processes 64/LPR rows per load issue. Inactive
// lanes carry sv=0/wv=0 so tail rows need no guard (w=0 kills the term,
// row 0 is always valid memory). Partial sums per lane-group are combined
// once per node with a shfl_xor butterfly.
template <int NW, bool RELU>
__global__ __launch_bounds__(256) void gather_kernel(const int* __restrict__ rowptr,
                                                     const unsigned short* __restrict__ srcs,
                                                     const float* __restrict__ dinv,
                                                     const unsigned short* __restrict__ h,
                                                     const float* __restrict__ b,
                                                     float* __restrict__ out, int M) {
    constexpr int LPR = NW / 8;        // lanes per source row (16 / 8)
    constexpr int RPW = 64 / LPR;      // rows per wave-step   (4  / 8)
    const int lane = threadIdx.x & 63;
    const int wid  = threadIdx.x >> 6;
    const int t    = blockIdx.x * 4 + wid;
    if (t >= M) return;
    const int sl = lane % LPR;         // column slice: cols [sl*8, sl*8+8)
    const int sr = lane / LPR;         // sub-row within wave-step

    float acc[8];
#pragma unroll
    for (int c = 0; c < 8; c++) acc[c] = 0.f;

    const int beg = rowptr[t], end = rowptr[t + 1];
    for (int eb = beg; eb < end; eb += 64) {
        const int rem = end - eb;
        int   sv = 0;
        float wv = 0.f;
        if (lane < rem) { sv = (int)srcs[eb + lane]; wv = dinv[sv]; }
        const int m = rem < 64 ? rem : 64;
        for (int j = 0; j < m; j += RPW) {
            int   s = __shfl(sv, j + sr);
            float w = __shfl(wv, j + sr);
            bf16x8 hv = *reinterpret_cast<const bf16x8*>(h + (size_t)s * NW + sl * 8);
#pragma unroll
            for (int c = 0; c < 8; c++)
                acc[c] += w * bfu_to_f((unsigned short)hv[c]);
        }
    }

    // combine the 64/LPR sub-row partials (butterfly -> all lanes hold total)
#pragma unroll
    for (int off = LPR; off < 64; off <<= 1)
#pragma unroll
        for (int c = 0; c < 8; c++) acc[c] += __shfl_xor(acc[c], off);

    if (sr == 0) {
        const float di = dinv[t];
        bf16x8 own = *reinterpret_cast<const bf16x8*>(h + (size_t)t * NW + sl * 8);
        float4 b0 = *reinterpret_cast<const float4*>(b + sl * 8);
        float4 b1 = *reinterpret_cast<const float4*>(b + sl * 8 + 4);
        float v[8];
#pragma unroll
        for (int c = 0; c < 8; c++) {
            float bc = (c < 4) ? (&b0.x)[c] : (&b1.x)[c - 4];
            v[c] = acc[c] * di + bfu_to_f((unsigned short)own[c]) * di * di + bc;
            if (RELU) v[c] = fmaxf(v[c], 0.f);
        }
        float* op = out + (size_t)t * NW + sl * 8;
        *reinterpret_cast<float4*>(op)     = make_float4(v[0], v[1], v[2], v[3]);
        *reinterpret_cast<float4*>(op + 4) = make_float4(v[4], v[5], v[6], v[7]);
    }
}

extern "C" void kernel_launch(void* const* d_in, const int* in_sizes, int n_in,
                              void* d_out, int out_size, void* d_ws, size_t ws_size,
                              hipStream_t stream) {
    const float* x  = (const float*)d_in[0];
    const int*   ei = (const int*)d_in[1];
    const float* W1 = (const float*)d_in[2];
    const float* b1 = (const float*)d_in[3];
    const float* W2 = (const float*)d_in[4];
    const float* b2 = (const float*)d_in[5];

    float* out_h2 = (float*)d_out;                 // [NN x 64]
    float* out_h1 = out_h2 + (size_t)NN * 64;      // [NN x 128]

    const int* src = ei;
    const int* dst = ei + NE;

    // ws layout (4B words):
    int*   wsw    = (int*)d_ws;
    int*   cnt    = wsw;                        // 8*NN2 = 400384
    int*   roff   = wsw + 400384;               // 8*NN2 = 400384
    int*   pos    = wsw + 800768;               // NE = 800000
    int*   rowptr = wsw + 1600768;              // 50064
    float* dinv   = (float*)(wsw + 1650832);    // NN2
    int*   deg    = wsw + 1700880;              // NN2
    int*   bsum   = wsw + 1750928;              // 64
    unsigned short* srcs = (unsigned short*)(wsw + 1750992);  // u16 [NE] = 400000 words
    unsigned short* T    = (unsigned short*)(wsw + 2150992);  // bf16 [NN x 128]
    unsigned short* wt1h = (unsigned short*)(wsw + 5350992);  // [128x128]
    unsigned short* wt1l = (unsigned short*)(wsw + 5359184);  // [128x128]
    unsigned short* wt2h = (unsigned short*)(wsw + 5367376);  // [64x128]
    unsigned short* wt2l = (unsigned short*)(wsw + 5371472);  // [64x128]

    // ----- W split/transpose prep + cnt zeroing (one launch, no memset) -----
    wprep_kernel<<<96 + ZB, 256, 0, stream>>>(W1, W2, wt1h, wt1l, wt2h, wt2l, cnt);

    // ----- fused: layer-1 MFMA GEMM + 8-replica rank histogram (overlapped) -----
    mfma_gemm_kernel<128, true><<<GB + RANK4_BLOCKS, 256, 0, stream>>>(
        x, wt1h, wt1l, T, NN, dst, cnt, pos);

    // ----- CSR: distributed reduce -> fill (tops inline) -> place (atomic-free) -----
    reduce_kernel<<<NB, 256, 0, stream>>>(cnt, deg, roff, dinv, bsum, NN);
    fill_kernel<<<NB, 256, 0, stream>>>(deg, bsum, rowptr, NN);
    place_kernel<<<RANK_BLOCKS, 256, 0, stream>>>(src, dst, rowptr, roff, pos, srcs, NE);

    const int aB = (NN + 3) / 4;

    // ----- layer 1 gather -----
    gather_kernel<128, true><<<aB, 256, 0, stream>>>(rowptr, srcs, dinv, T,
                                                     b1, out_h1, NN);
    // ----- layer 2 -----
    mfma_gemm_kernel<64, false><<<GB, 256, 0, stream>>>(
        out_h1, wt2h, wt2l, T, NN, nullptr, nullptr, nullptr);
    gather_kernel<64, false><<<aB, 256, 0, stream>>>(rowptr, srcs, dinv, T,
                                                     b2, out_h2, NN);
}